// Round 7
// baseline (228.378 us; speedup 1.0000x reference)
//
#include <hip/hip_runtime.h>
#include <cstdint>

// Exact radix-select on order-transformed x bits among t<0 entries
// (t = -1 exactly => negative_loss = softplus(x), strictly increasing in x).
// R7: k1 is a PURE stream-compactor (no LDS histogram in the 82 MB pass):
// LDS-staged, coalesced flush to one dense global array. The 2048-bin level-1
// hist (k1b) and the 2^21-bin level-2 hist (k2) both read only the ~13.6 MB
// compact array. Final pass: fast __expf/__logf values, exact bit-compare
// mask, precise log1pf re-check within a 256-ulp guard band at the boundary.
//
// ws layout:
//   [0     ..  8192)   hist1  (2048 u32)  bits [31:21]
//   [8192  .. 12288)   csums  (1024 u32)  per-chunk sums of hist21
//   [12288 .. 12352)   SelState
//   [12416 .. 12420)   gcur (compact-array cursor)
//   [32768 .. 32768+8MB)   hist21 (2^21 u32)  bits [20:0]
//   [32768+8MB .. +4N)     compact u-vals (dense, arbitrary order)

struct SelState {
    uint32_t prefix;   // 11-bit level-1 prefix
    uint32_t k_rem;    // remaining rank within selected bin
    uint32_t u_kth;    // final: transformed bits of k-th largest x
    float    thr_nl;   // final: precise loss-space threshold
    uint32_t done;
};

#define GUARD 256u

__device__ __forceinline__ uint32_t xform(uint32_t b) {
    return ((int32_t)b < 0) ? ~b : (b | 0x80000000u);
}
__device__ __forceinline__ float unxform(uint32_t u) {
    uint32_t b = (u & 0x80000000u) ? (u ^ 0x80000000u) : ~u;
    return __uint_as_float(b);
}
// precise chain — matches reference fp32 semantics; used only for the
// threshold value and the rare guard-band compare.
__device__ __forceinline__ float neg_loss_precise(float x, float t) {
#pragma clang fp contract(off)
    return (fmaxf(-x, 0.0f) - x * t) + log1pf(expf(-fabsf(x)));
}

__device__ __forceinline__ void uquad(float4 xv, float4 tv, uint32_t* u) {
    u[0] = (tv.x < 0.0f) ? xform(__float_as_uint(xv.x)) : 0u;
    u[1] = (tv.y < 0.0f) ? xform(__float_as_uint(xv.y)) : 0u;
    u[2] = (tv.z < 0.0f) ? xform(__float_as_uint(xv.z)) : 0u;
    u[3] = (tv.w < 0.0f) ? xform(__float_as_uint(xv.w)) : 0u;
}

// ---------------- k1: pure stream-compact (no histogram) ----------------
__global__ __launch_bounds__(256) void k1_compact(
        const float* __restrict__ x, const float* __restrict__ t,
        uint32_t* __restrict__ comp, uint32_t* __restrict__ gcur, int n) {
    __shared__ uint32_t sbuf[2048];     // 8 KB: per-flush max = 256 thr x 8
    __shared__ uint32_t scount, sbase;
    if (threadIdx.x == 0) scount = 0u;
    __syncthreads();

    const float4* x4 = (const float4*)x;
    const float4* t4 = (const float4*)t;
    const int n4 = n >> 2;
    const int S = gridDim.x * 256;

    // stage up to 8 u's per thread, then block-flush (coalesced).
    // NOTE: called by ALL threads of the block (contains barriers).
    auto stage8 = [&](const uint32_t* ua, const uint32_t* ub) {
        uint32_t loc[8];
        int c = 0;
#pragma unroll
        for (int j = 0; j < 4; ++j) if (ua[j]) loc[c++] = ua[j];
#pragma unroll
        for (int j = 0; j < 4; ++j) if (ub[j]) loc[c++] = ub[j];
        uint32_t pos = 0;
        if (c) pos = atomicAdd(&scount, (uint32_t)c);
        for (int j = 0; j < c; ++j) sbuf[pos + j] = loc[j];
        __syncthreads();
        uint32_t cnt = scount;
        __syncthreads();
        if (threadIdx.x == 0) { sbase = atomicAdd(gcur, cnt); scount = 0u; }
        __syncthreads();
        for (uint32_t j = threadIdx.x; j < cnt; j += 256u) comp[sbase + j] = sbuf[j];
        __syncthreads();
    };

    int ib = blockIdx.x * 256;                     // block-uniform base
    for (; ib + 3 * S + 256 <= n4; ib += 4 * S) {  // uniform trip count
        const int i = ib + threadIdx.x;
        float4 xa = x4[i], xb = x4[i + S], xc = x4[i + 2 * S], xd = x4[i + 3 * S];
        float4 ta = t4[i], tb = t4[i + S], tc = t4[i + 2 * S], td = t4[i + 3 * S];
        uint32_t ua[4], ub[4], uc[4], ud[4];
        uquad(xa, ta, ua); uquad(xb, tb, ub); uquad(xc, tc, uc); uquad(xd, td, ud);
        stage8(ua, ub);
        stage8(uc, ud);
    }
    for (; ib < n4; ib += S) {                     // block-uniform remainder
        const int i = ib + threadIdx.x;
        uint32_t ua[4] = {0u, 0u, 0u, 0u}, uz[4] = {0u, 0u, 0u, 0u};
        if (i < n4) { float4 xa = x4[i], ta = t4[i]; uquad(xa, ta, ua); }
        stage8(ua, uz);
    }
    if (blockIdx.x == 0) {                         // n % 4 tail (<= 3 elems)
        const int j = (n4 << 2) + threadIdx.x;
        uint32_t u = (j < n && t[j] < 0.0f) ? xform(__float_as_uint(x[j])) : 0u;
        uint32_t ua[4] = {u, 0u, 0u, 0u}, uz[4] = {0u, 0u, 0u, 0u};
        stage8(ua, uz);
    }
}

// ---------------- k1b: 2048-bin hist from compact array ----------------
__global__ __launch_bounds__(256) void k1b_hist(
        const float* __restrict__ x, const float* __restrict__ t,
        const uint32_t* __restrict__ comp, const uint32_t* __restrict__ gcur,
        uint32_t* __restrict__ hist, int n) {
    __shared__ uint32_t lh[2 * 2048];
    for (int i = threadIdx.x; i < 2 * 2048; i += 256) lh[i] = 0;
    __syncthreads();
    uint32_t* my = &lh[(threadIdx.x & 1) * 2048];

    if (comp) {
        const uint32_t total = *gcur;
        const uint32_t tq = total >> 2;
        const uint4* c4 = (const uint4*)comp;
        const uint32_t S = gridDim.x * 256;
        for (uint32_t i = blockIdx.x * 256 + threadIdx.x; i < tq; i += S) {
            uint4 v = c4[i];
            atomicAdd(&my[v.x >> 21], 1u);
            atomicAdd(&my[v.y >> 21], 1u);
            atomicAdd(&my[v.z >> 21], 1u);
            atomicAdd(&my[v.w >> 21], 1u);
        }
        if (blockIdx.x == 0) {
            for (uint32_t j = (tq << 2) + threadIdx.x; j < total; j += 256u)
                atomicAdd(&my[comp[j] >> 21], 1u);
        }
    } else {  // fallback: read x,t directly
        const float4* x4 = (const float4*)x;
        const float4* t4 = (const float4*)t;
        const int n4 = n >> 2;
        const int S = gridDim.x * 256;
        for (int i = blockIdx.x * 256 + threadIdx.x; i < n4; i += S) {
            float4 xv = x4[i], tv = t4[i];
            uint32_t u[4]; uquad(xv, tv, u);
#pragma unroll
            for (int j = 0; j < 4; ++j) if (u[j]) atomicAdd(&my[u[j] >> 21], 1u);
        }
        if (blockIdx.x == 0) {
            for (int j = (n4 << 2) + threadIdx.x; j < n; j += 256) {
                uint32_t u = (t[j] < 0.0f) ? xform(__float_as_uint(x[j])) : 0u;
                if (u) atomicAdd(&my[u >> 21], 1u);
            }
        }
    }
    __syncthreads();
    for (int b = threadIdx.x; b < 2048; b += 256) {
        uint32_t c = lh[b] + lh[2048 + b];
        if (c) atomicAdd(&hist[b], c);
    }
}

// ---------------- scan1: 1 block, pick 11-bit prefix ----------------
__global__ __launch_bounds__(256) void scan1(
        const uint32_t* __restrict__ hist, SelState* __restrict__ st,
        const int* __restrict__ kptr) {
    __shared__ uint32_t part[256];
    const int tid = threadIdx.x;
    uint32_t cnt[8];
    uint32_t lsum = 0;
#pragma unroll
    for (int j = 0; j < 8; ++j) { cnt[j] = hist[tid * 8 + j]; lsum += cnt[j]; }
    part[tid] = lsum;
    __syncthreads();
    for (int off = 1; off < 256; off <<= 1) {   // inclusive suffix sum
        uint32_t add = (tid + off < 256) ? part[tid + off] : 0u;
        __syncthreads();
        part[tid] += add;
        __syncthreads();
    }
    const uint32_t total = part[0];
    int kk = *kptr;
    uint32_t k = (kk > 0) ? (uint32_t)kk : 0u;
    if (k == 0u) {   // keep all negatives
        if (tid == 0) { st->u_kth = 0xFFFFFFFFu; st->thr_nl = __int_as_float(0x7F800000); st->done = 1u; }
        return;
    }
    if (k > total) { // drop all negatives
        if (tid == 0) { st->u_kth = 0u; st->thr_nl = 0.0f; st->done = 1u; }
        return;
    }
    uint32_t A = (tid < 255) ? part[tid + 1] : 0u;  // strictly-above count
#pragma unroll
    for (int j = 7; j >= 0; --j) {
        uint32_t c = cnt[j];
        if (A < k && k <= A + c) {   // exactly one (thread,bin)
            st->prefix = (uint32_t)(tid * 8 + j);
            st->k_rem = k - A;       // done stays 0 (memset)
        }
        A += c;
    }
}

// ---------------- k2: 21-bit global hist from compact array ----------------
__global__ __launch_bounds__(256) void k2_hist21(
        const float* __restrict__ x, const float* __restrict__ t,
        const uint32_t* __restrict__ comp, const uint32_t* __restrict__ gcur,
        uint32_t* __restrict__ h21, const SelState* __restrict__ st, int n) {
    __shared__ uint32_t s_pref, s_done;
    if (threadIdx.x == 0) { s_pref = st->prefix; s_done = st->done; }
    __syncthreads();
    if (s_done) return;
    const uint32_t pref = s_pref;

    if (comp) {
        const uint32_t total = *gcur;
        const uint32_t tq = total >> 2;
        const uint4* c4 = (const uint4*)comp;
        const uint32_t S = gridDim.x * 256;
        for (uint32_t i = blockIdx.x * 256 + threadIdx.x; i < tq; i += S) {
            uint4 v = c4[i];
            if ((v.x >> 21) == pref) atomicAdd(&h21[v.x & 0x1FFFFFu], 1u);
            if ((v.y >> 21) == pref) atomicAdd(&h21[v.y & 0x1FFFFFu], 1u);
            if ((v.z >> 21) == pref) atomicAdd(&h21[v.z & 0x1FFFFFu], 1u);
            if ((v.w >> 21) == pref) atomicAdd(&h21[v.w & 0x1FFFFFu], 1u);
        }
        if (blockIdx.x == 0) {
            for (uint32_t j = (tq << 2) + threadIdx.x; j < total; j += 256u) {
                uint32_t u = comp[j];
                if ((u >> 21) == pref) atomicAdd(&h21[u & 0x1FFFFFu], 1u);
            }
        }
    } else {  // fallback: read x,t directly
        const float4* x4 = (const float4*)x;
        const float4* t4 = (const float4*)t;
        const int n4 = n >> 2;
        const int S = gridDim.x * 256;
        for (int i = blockIdx.x * 256 + threadIdx.x; i < n4; i += S) {
            float4 xv = x4[i], tv = t4[i];
            uint32_t u[4]; uquad(xv, tv, u);
#pragma unroll
            for (int j = 0; j < 4; ++j)
                if (u[j] && (u[j] >> 21) == pref) atomicAdd(&h21[u[j] & 0x1FFFFFu], 1u);
        }
        if (blockIdx.x == 0) {
            for (int j = (n4 << 2) + threadIdx.x; j < n; j += 256) {
                uint32_t u = (t[j] < 0.0f) ? xform(__float_as_uint(x[j])) : 0u;
                if (u && (u >> 21) == pref) atomicAdd(&h21[u & 0x1FFFFFu], 1u);
            }
        }
    }
}

// ---------------- scan2a: per-chunk sums of hist21 (1024 x 2048) ----------------
__global__ __launch_bounds__(256) void scan2a(
        const uint32_t* __restrict__ h21, uint32_t* __restrict__ csums,
        const SelState* __restrict__ st) {
    __shared__ uint32_t red[256];
    __shared__ uint32_t s_done;
    if (threadIdx.x == 0) s_done = st->done;
    __syncthreads();
    if (s_done) return;   // csums stays 0 (memset) — unused on this path
    const uint4* b4 = (const uint4*)(h21 + (size_t)blockIdx.x * 2048);
    uint32_t s = 0;
    for (int j = threadIdx.x; j < 512; j += 256) {
        uint4 v = b4[j];
        s += v.x + v.y + v.z + v.w;
    }
    red[threadIdx.x] = s;
    __syncthreads();
    for (int off = 128; off > 0; off >>= 1) {
        if (threadIdx.x < off) red[threadIdx.x] += red[threadIdx.x + off];
        __syncthreads();
    }
    if (threadIdx.x == 0) csums[blockIdx.x] = red[0];
}

// ---------------- scan2b: 1 block, pick chunk then bin -> u_kth ----------------
__global__ __launch_bounds__(256) void scan2b(
        const uint32_t* __restrict__ h21, const uint32_t* __restrict__ csums,
        SelState* __restrict__ st) {
    __shared__ uint32_t part[256];
    __shared__ uint32_t sel[2];
    __shared__ SelState sst;
    const int tid = threadIdx.x;
    if (tid == 0) sst = *st;
    __syncthreads();
    if (sst.done) return;
    const uint32_t k = sst.k_rem;

    // stage 1: 1024 chunk sums, 4 per thread
    uint32_t c4[4];
    uint32_t lsum = 0;
#pragma unroll
    for (int j = 0; j < 4; ++j) { c4[j] = csums[tid * 4 + j]; lsum += c4[j]; }
    part[tid] = lsum;
    __syncthreads();
    for (int off = 1; off < 256; off <<= 1) {
        uint32_t add = (tid + off < 256) ? part[tid + off] : 0u;
        __syncthreads();
        part[tid] += add;
        __syncthreads();
    }
    uint32_t A = (tid < 255) ? part[tid + 1] : 0u;
#pragma unroll
    for (int j = 3; j >= 0; --j) {
        uint32_t c = c4[j];
        if (A < k && k <= A + c) { sel[0] = (uint32_t)(tid * 4 + j); sel[1] = k - A; }
        A += c;
    }
    __syncthreads();
    const uint32_t chunk = sel[0];
    const uint32_t k2 = sel[1];
    __syncthreads();

    // stage 2: 2048 bins of the chosen chunk, 8 per thread
    const uint32_t* base = h21 + (size_t)chunk * 2048;
    uint32_t b8[8];
    lsum = 0;
#pragma unroll
    for (int j = 0; j < 8; ++j) { b8[j] = base[tid * 8 + j]; lsum += b8[j]; }
    part[tid] = lsum;
    __syncthreads();
    for (int off = 1; off < 256; off <<= 1) {
        uint32_t add = (tid + off < 256) ? part[tid + off] : 0u;
        __syncthreads();
        part[tid] += add;
        __syncthreads();
    }
    A = (tid < 255) ? part[tid + 1] : 0u;
#pragma unroll
    for (int j = 7; j >= 0; --j) {
        uint32_t c = b8[j];
        if (A < k2 && k2 <= A + c) {
            uint32_t u = (sst.prefix << 21) | (chunk * 2048u + (uint32_t)(tid * 8 + j));
            st->u_kth = u;
            st->thr_nl = neg_loss_precise(unxform(u), -1.0f);  // t = -1 exactly
            st->done = 1u;
        }
        A += c;
    }
}

// ---------------- final: fast-math values, bit-exact mask ----------------
__device__ __forceinline__ float fin1(float xx, float tt, uint32_t ukth, float thr) {
    float lp = __logf(1.0f + __expf(-fabsf(xx)));   // HW exp/log
    float v = 0.0f;
    if (tt > 0.0f) {
        v = fmaxf(xx, 0.0f) - xx * tt + lp;
    } else if (tt < 0.0f) {
        uint32_t u = xform(__float_as_uint(xx));
        bool keep = u < ukth;
        if (keep && (ukth - u) < GUARD)             // ~0 lanes hit this
            keep = neg_loss_precise(xx, tt) < thr;
        if (keep) v = fmaxf(-xx, 0.0f) - xx * tt + lp;
    }
    return v;
}

__device__ __forceinline__ float4 fin_quad(float4 xv, float4 tv, uint32_t ukth, float thr) {
    float4 r;
    r.x = fin1(xv.x, tv.x, ukth, thr);
    r.y = fin1(xv.y, tv.y, ukth, thr);
    r.z = fin1(xv.z, tv.z, ukth, thr);
    r.w = fin1(xv.w, tv.w, ukth, thr);
    return r;
}

__global__ __launch_bounds__(256) void k_final(
        const float* __restrict__ x, const float* __restrict__ t,
        const SelState* __restrict__ st, float* __restrict__ out, int n) {
    const uint32_t ukth = st->u_kth;
    const float thr = st->thr_nl;
    const float4* x4 = (const float4*)x;
    const float4* t4 = (const float4*)t;
    float4* o4 = (float4*)out;
    const int n4 = n >> 2;
    const int S = gridDim.x * 256;
    int i = blockIdx.x * 256 + threadIdx.x;
    for (; i + 3 * S < n4; i += 4 * S) {
        float4 xa = x4[i], xb = x4[i + S], xc = x4[i + 2 * S], xd = x4[i + 3 * S];
        float4 ta = t4[i], tb = t4[i + S], tc = t4[i + 2 * S], td = t4[i + 3 * S];
        o4[i]         = fin_quad(xa, ta, ukth, thr);
        o4[i + S]     = fin_quad(xb, tb, ukth, thr);
        o4[i + 2 * S] = fin_quad(xc, tc, ukth, thr);
        o4[i + 3 * S] = fin_quad(xd, td, ukth, thr);
    }
    for (; i < n4; i += S) {
        float4 xa = x4[i], ta = t4[i];
        o4[i] = fin_quad(xa, ta, ukth, thr);
    }
    if (blockIdx.x == 0) {
        for (int j = (n4 << 2) + threadIdx.x; j < n; j += 256) {
            out[j] = fin1(x[j], t[j], ukth, thr);
        }
    }
}

extern "C" void kernel_launch(void* const* d_in, const int* in_sizes, int n_in,
                              void* d_out, int out_size, void* d_ws, size_t ws_size,
                              hipStream_t stream) {
    const float* x = (const float*)d_in[0];
    const float* t = (const float*)d_in[1];
    const int* kptr = (const int*)d_in[2];
    float* out = (float*)d_out;
    const int n = in_sizes[0];
    if (n <= 0) return;

    char* ws = (char*)d_ws;
    uint32_t* hist1 = (uint32_t*)(ws + 0);        // 2048 bins
    uint32_t* csums = (uint32_t*)(ws + 8192);     // 1024 chunk sums
    SelState* st    = (SelState*)(ws + 12288);
    uint32_t* gcur  = (uint32_t*)(ws + 12416);
    uint32_t* h21   = (uint32_t*)(ws + 32768);    // 2^21 bins (8 MB)
    const size_t h21_end = 32768 + (size_t)(1u << 21) * 4u;
    const size_t need = h21_end + (size_t)n * 4u;
    uint32_t* comp = (ws_size >= need) ? (uint32_t*)(ws + h21_end) : nullptr;

    // zero meta (32 KB) + hist21 (8 MB) in one memset
    hipMemsetAsync(d_ws, 0, h21_end, stream);

    const int n4 = n >> 2;
    int work = (n4 + 255) / 256;
    if (work < 1) work = 1;
    int gridC = work < 2048 ? work : 2048;   // compaction / final
    int gridS = work < 512 ? work : 512;     // compact-array consumers

    k1_compact<<<gridC, 256, 0, stream>>>(x, t, comp, gcur, n);
    k1b_hist  <<<gridS, 256, 0, stream>>>(x, t, comp, gcur, hist1, n);
    scan1     <<<1, 256, 0, stream>>>(hist1, st, kptr);
    k2_hist21 <<<gridS, 256, 0, stream>>>(x, t, comp, gcur, h21, st, n);
    scan2a    <<<1024, 256, 0, stream>>>(h21, csums, st);
    scan2b    <<<1, 256, 0, stream>>>(h21, csums, st);
    k_final   <<<gridC, 256, 0, stream>>>(x, t, st, out, n);
}

// Round 8
// 194.852 us; speedup vs baseline: 1.1721x; 1.1721x over previous
//
#include <hip/hip_runtime.h>
#include <cstdint>

// Exact radix-select on order-transformed x bits among t<0 entries
// (t = -1 exactly => negative_loss = softplus(x), strictly increasing in x).
// R8: the 82-MB pass is a WAVE-level compactor: no LDS, no barriers.
// Per-lane register staging (up to 8), wave shfl-prefix, ONE global atomic
// per wave-chunk on a per-block cursor, direct coalesced stores into the
// block's segment. Level-1 hist (2048 bins) and level-2 hist (2^21 bins) are
// built from the ~13.6 MB compact array. Final pass: fast __expf/__logf
// values, exact bit-compare mask, precise log1pf re-check within a 256-ulp
// guard band at the boundary.
//
// ws layout:
//   [0     ..  8192)   hist1  (2048 u32)  bits [31:21]
//   [8192  .. 12288)   csums  (1024 u32)  per-chunk sums of hist21
//   [12288 .. 12352)   SelState
//   [16384 .. 24576)   bcount (2048 u32) per-block segment cursors
//   [32768 .. 32768+8MB)   hist21 (2^21 u32)  bits [20:0]
//   [32768+8MB .. )        comp segments (cap u32 per block)

struct SelState {
    uint32_t prefix;   // 11-bit level-1 prefix
    uint32_t k_rem;    // remaining rank within selected bin
    uint32_t u_kth;    // final: transformed bits of k-th largest x
    float    thr_nl;   // final: precise loss-space threshold
    uint32_t done;
};

#define GUARD 256u

__device__ __forceinline__ uint32_t xform(uint32_t b) {
    return ((int32_t)b < 0) ? ~b : (b | 0x80000000u);
}
__device__ __forceinline__ float unxform(uint32_t u) {
    uint32_t b = (u & 0x80000000u) ? (u ^ 0x80000000u) : ~u;
    return __uint_as_float(b);
}
// precise chain — matches reference fp32 semantics; used only for the
// threshold value and the rare guard-band compare.
__device__ __forceinline__ float neg_loss_precise(float x, float t) {
#pragma clang fp contract(off)
    return (fmaxf(-x, 0.0f) - x * t) + log1pf(expf(-fabsf(x)));
}

// ---------------- k1: wave-level stream compaction (no LDS, no barriers) ----
__global__ __launch_bounds__(256) void k1_compact(
        const float* __restrict__ x, const float* __restrict__ t,
        uint32_t* __restrict__ comp, uint32_t* __restrict__ bcount,
        uint32_t cap, int n) {
    const int n4 = n >> 2;
    const int S = gridDim.x * 256;
    uint32_t* __restrict__ seg = comp + (size_t)blockIdx.x * cap;
    uint32_t* __restrict__ cur = &bcount[blockIdx.x];
    const float4* __restrict__ x4 = (const float4*)x;
    const float4* __restrict__ t4 = (const float4*)t;
    const int lane = threadIdx.x & 63;

    for (int ib = blockIdx.x * 256; ib < n4; ib += 2 * S) {   // block-uniform trips
        const int i1 = ib + threadIdx.x;
        const int i2 = i1 + S;
        const bool v1 = i1 < n4, v2 = i2 < n4;
        float4 xa, ta, xb, tb;
        if (v1) { xa = x4[i1]; ta = t4[i1]; }
        if (v2) { xb = x4[i2]; tb = t4[i2]; }
        uint32_t loc[8];
        int c = 0;
        if (v1) {
            uint32_t u;
            u = (ta.x < 0.0f) ? xform(__float_as_uint(xa.x)) : 0u; if (u) loc[c++] = u;
            u = (ta.y < 0.0f) ? xform(__float_as_uint(xa.y)) : 0u; if (u) loc[c++] = u;
            u = (ta.z < 0.0f) ? xform(__float_as_uint(xa.z)) : 0u; if (u) loc[c++] = u;
            u = (ta.w < 0.0f) ? xform(__float_as_uint(xa.w)) : 0u; if (u) loc[c++] = u;
        }
        if (v2) {
            uint32_t u;
            u = (tb.x < 0.0f) ? xform(__float_as_uint(xb.x)) : 0u; if (u) loc[c++] = u;
            u = (tb.y < 0.0f) ? xform(__float_as_uint(xb.y)) : 0u; if (u) loc[c++] = u;
            u = (tb.z < 0.0f) ? xform(__float_as_uint(xb.z)) : 0u; if (u) loc[c++] = u;
            u = (tb.w < 0.0f) ? xform(__float_as_uint(xb.w)) : 0u; if (u) loc[c++] = u;
        }
        // wave-level compaction: shfl prefix over per-lane counts
        if (__ballot(c > 0)) {               // wave-uniform branch
            int pfx = c;
#pragma unroll
            for (int off = 1; off < 64; off <<= 1) {
                int vv = __shfl_up(pfx, off);
                if (lane >= off) pfx += vv;
            }
            const int tot = __shfl(pfx, 63);
            uint32_t base = 0;
            if (lane == 63) base = atomicAdd(cur, (uint32_t)tot);
            base = __shfl(base, 63);
            uint32_t o = base + (uint32_t)(pfx - c);
            for (int j = 0; j < c; ++j) seg[o + j] = loc[j];
        }
    }
    if (blockIdx.x == 0) {                   // n % 4 tail (<= 3 elems)
        const int j = (n4 << 2) + threadIdx.x;
        uint32_t u = 0;
        if (j < n && t[j] < 0.0f) u = xform(__float_as_uint(x[j]));
        const int c = u ? 1 : 0;
        if (__ballot(c > 0)) {
            int pfx = c;
#pragma unroll
            for (int off = 1; off < 64; off <<= 1) {
                int vv = __shfl_up(pfx, off);
                if (lane >= off) pfx += vv;
            }
            const int tot = __shfl(pfx, 63);
            uint32_t base = 0;
            if (lane == 63) base = atomicAdd(cur, (uint32_t)tot);
            base = __shfl(base, 63);
            if (c) seg[base + (uint32_t)(pfx - 1)] = u;
        }
    }
}

// ---------------- k1b: 2048-bin hist from compact segments ----------------
__global__ __launch_bounds__(256) void k1b_hist(
        const uint32_t* __restrict__ comp, const uint32_t* __restrict__ bcount,
        uint32_t cap, uint32_t* __restrict__ hist,
        const float* __restrict__ x, const float* __restrict__ t, int n) {
    __shared__ uint32_t lh[2 * 2048];
    for (int i = threadIdx.x; i < 2 * 2048; i += 256) lh[i] = 0;
    __syncthreads();
    uint32_t* my = &lh[(threadIdx.x & 1) * 2048];

    if (comp) {
        const uint32_t cnt = bcount[blockIdx.x];
        const uint32_t* __restrict__ seg = comp + (size_t)blockIdx.x * cap;
        uint32_t j = threadIdx.x;
        for (; j + 768u < cnt; j += 1024u) {   // 4 loads in flight
            uint32_t a = seg[j], b = seg[j + 256], c = seg[j + 512], d = seg[j + 768];
            atomicAdd(&my[a >> 21], 1u);
            atomicAdd(&my[b >> 21], 1u);
            atomicAdd(&my[c >> 21], 1u);
            atomicAdd(&my[d >> 21], 1u);
        }
        for (; j < cnt; j += 256u) atomicAdd(&my[seg[j] >> 21], 1u);
    } else {  // fallback: read x,t directly
        const float4* x4 = (const float4*)x;
        const float4* t4 = (const float4*)t;
        const int n4 = n >> 2;
        const int S = gridDim.x * 256;
        for (int i = blockIdx.x * 256 + threadIdx.x; i < n4; i += S) {
            float4 xv = x4[i], tv = t4[i];
            uint32_t u;
            u = (tv.x < 0.0f) ? xform(__float_as_uint(xv.x)) : 0u; if (u) atomicAdd(&my[u >> 21], 1u);
            u = (tv.y < 0.0f) ? xform(__float_as_uint(xv.y)) : 0u; if (u) atomicAdd(&my[u >> 21], 1u);
            u = (tv.z < 0.0f) ? xform(__float_as_uint(xv.z)) : 0u; if (u) atomicAdd(&my[u >> 21], 1u);
            u = (tv.w < 0.0f) ? xform(__float_as_uint(xv.w)) : 0u; if (u) atomicAdd(&my[u >> 21], 1u);
        }
        if (blockIdx.x == 0) {
            for (int j = (n4 << 2) + threadIdx.x; j < n; j += 256) {
                uint32_t u = (t[j] < 0.0f) ? xform(__float_as_uint(x[j])) : 0u;
                if (u) atomicAdd(&my[u >> 21], 1u);
            }
        }
    }
    __syncthreads();
    for (int b = threadIdx.x; b < 2048; b += 256) {
        uint32_t c = lh[b] + lh[2048 + b];
        if (c) atomicAdd(&hist[b], c);
    }
}

// ---------------- scan1: 1 block, pick 11-bit prefix ----------------
__global__ __launch_bounds__(256) void scan1(
        const uint32_t* __restrict__ hist, SelState* __restrict__ st,
        const int* __restrict__ kptr) {
    __shared__ uint32_t part[256];
    const int tid = threadIdx.x;
    uint32_t cnt[8];
    uint32_t lsum = 0;
#pragma unroll
    for (int j = 0; j < 8; ++j) { cnt[j] = hist[tid * 8 + j]; lsum += cnt[j]; }
    part[tid] = lsum;
    __syncthreads();
    for (int off = 1; off < 256; off <<= 1) {   // inclusive suffix sum
        uint32_t add = (tid + off < 256) ? part[tid + off] : 0u;
        __syncthreads();
        part[tid] += add;
        __syncthreads();
    }
    const uint32_t total = part[0];
    int kk = *kptr;
    uint32_t k = (kk > 0) ? (uint32_t)kk : 0u;
    if (k == 0u) {   // keep all negatives
        if (tid == 0) { st->u_kth = 0xFFFFFFFFu; st->thr_nl = __int_as_float(0x7F800000); st->done = 1u; }
        return;
    }
    if (k > total) { // drop all negatives
        if (tid == 0) { st->u_kth = 0u; st->thr_nl = 0.0f; st->done = 1u; }
        return;
    }
    uint32_t A = (tid < 255) ? part[tid + 1] : 0u;  // strictly-above count
#pragma unroll
    for (int j = 7; j >= 0; --j) {
        uint32_t c = cnt[j];
        if (A < k && k <= A + c) {   // exactly one (thread,bin)
            st->prefix = (uint32_t)(tid * 8 + j);
            st->k_rem = k - A;       // done stays 0 (memset)
        }
        A += c;
    }
}

// ---------------- k2: 21-bit global hist of prefix-matching elems ----------
__global__ __launch_bounds__(256) void k2_hist21(
        const uint32_t* __restrict__ comp, const uint32_t* __restrict__ bcount,
        uint32_t cap, uint32_t* __restrict__ h21, const SelState* __restrict__ st,
        const float* __restrict__ x, const float* __restrict__ t, int n) {
    __shared__ uint32_t s_pref, s_done;
    if (threadIdx.x == 0) { s_pref = st->prefix; s_done = st->done; }
    __syncthreads();
    if (s_done) return;
    const uint32_t pref = s_pref;

    if (comp) {
        const uint32_t cnt = bcount[blockIdx.x];
        const uint32_t* __restrict__ seg = comp + (size_t)blockIdx.x * cap;
        uint32_t j = threadIdx.x;
        for (; j + 768u < cnt; j += 1024u) {
            uint32_t a = seg[j], b = seg[j + 256], c = seg[j + 512], d = seg[j + 768];
            if ((a >> 21) == pref) atomicAdd(&h21[a & 0x1FFFFFu], 1u);
            if ((b >> 21) == pref) atomicAdd(&h21[b & 0x1FFFFFu], 1u);
            if ((c >> 21) == pref) atomicAdd(&h21[c & 0x1FFFFFu], 1u);
            if ((d >> 21) == pref) atomicAdd(&h21[d & 0x1FFFFFu], 1u);
        }
        for (; j < cnt; j += 256u) {
            uint32_t a = seg[j];
            if ((a >> 21) == pref) atomicAdd(&h21[a & 0x1FFFFFu], 1u);
        }
    } else {  // fallback: read x,t directly
        const float4* x4 = (const float4*)x;
        const float4* t4 = (const float4*)t;
        const int n4 = n >> 2;
        const int S = gridDim.x * 256;
        for (int i = blockIdx.x * 256 + threadIdx.x; i < n4; i += S) {
            float4 xv = x4[i], tv = t4[i];
            uint32_t u;
            u = (tv.x < 0.0f) ? xform(__float_as_uint(xv.x)) : 0u;
            if (u && (u >> 21) == pref) atomicAdd(&h21[u & 0x1FFFFFu], 1u);
            u = (tv.y < 0.0f) ? xform(__float_as_uint(xv.y)) : 0u;
            if (u && (u >> 21) == pref) atomicAdd(&h21[u & 0x1FFFFFu], 1u);
            u = (tv.z < 0.0f) ? xform(__float_as_uint(xv.z)) : 0u;
            if (u && (u >> 21) == pref) atomicAdd(&h21[u & 0x1FFFFFu], 1u);
            u = (tv.w < 0.0f) ? xform(__float_as_uint(xv.w)) : 0u;
            if (u && (u >> 21) == pref) atomicAdd(&h21[u & 0x1FFFFFu], 1u);
        }
        if (blockIdx.x == 0) {
            for (int j = (n4 << 2) + threadIdx.x; j < n; j += 256) {
                uint32_t u = (t[j] < 0.0f) ? xform(__float_as_uint(x[j])) : 0u;
                if (u && (u >> 21) == pref) atomicAdd(&h21[u & 0x1FFFFFu], 1u);
            }
        }
    }
}

// ---------------- scan2a: per-chunk sums of hist21 (1024 x 2048) ----------
__global__ __launch_bounds__(256) void scan2a(
        const uint32_t* __restrict__ h21, uint32_t* __restrict__ csums,
        const SelState* __restrict__ st) {
    __shared__ uint32_t red[256];
    __shared__ uint32_t s_done;
    if (threadIdx.x == 0) s_done = st->done;
    __syncthreads();
    if (s_done) return;   // csums stays 0 (memset) — unused on this path
    const uint4* b4 = (const uint4*)(h21 + (size_t)blockIdx.x * 2048);
    uint32_t s = 0;
    for (int j = threadIdx.x; j < 512; j += 256) {
        uint4 v = b4[j];
        s += v.x + v.y + v.z + v.w;
    }
    red[threadIdx.x] = s;
    __syncthreads();
    for (int off = 128; off > 0; off >>= 1) {
        if (threadIdx.x < off) red[threadIdx.x] += red[threadIdx.x + off];
        __syncthreads();
    }
    if (threadIdx.x == 0) csums[blockIdx.x] = red[0];
}

// ---------------- scan2b: 1 block, pick chunk then bin -> u_kth ------------
__global__ __launch_bounds__(256) void scan2b(
        const uint32_t* __restrict__ h21, const uint32_t* __restrict__ csums,
        SelState* __restrict__ st) {
    __shared__ uint32_t part[256];
    __shared__ uint32_t sel[2];
    __shared__ SelState sst;
    const int tid = threadIdx.x;
    if (tid == 0) sst = *st;
    __syncthreads();
    if (sst.done) return;
    const uint32_t k = sst.k_rem;

    // stage 1: 1024 chunk sums, 4 per thread
    uint32_t c4[4];
    uint32_t lsum = 0;
#pragma unroll
    for (int j = 0; j < 4; ++j) { c4[j] = csums[tid * 4 + j]; lsum += c4[j]; }
    part[tid] = lsum;
    __syncthreads();
    for (int off = 1; off < 256; off <<= 1) {
        uint32_t add = (tid + off < 256) ? part[tid + off] : 0u;
        __syncthreads();
        part[tid] += add;
        __syncthreads();
    }
    uint32_t A = (tid < 255) ? part[tid + 1] : 0u;
#pragma unroll
    for (int j = 3; j >= 0; --j) {
        uint32_t c = c4[j];
        if (A < k && k <= A + c) { sel[0] = (uint32_t)(tid * 4 + j); sel[1] = k - A; }
        A += c;
    }
    __syncthreads();
    const uint32_t chunk = sel[0];
    const uint32_t k2 = sel[1];
    __syncthreads();

    // stage 2: 2048 bins of the chosen chunk, 8 per thread
    const uint32_t* base = h21 + (size_t)chunk * 2048;
    uint32_t b8[8];
    lsum = 0;
#pragma unroll
    for (int j = 0; j < 8; ++j) { b8[j] = base[tid * 8 + j]; lsum += b8[j]; }
    part[tid] = lsum;
    __syncthreads();
    for (int off = 1; off < 256; off <<= 1) {
        uint32_t add = (tid + off < 256) ? part[tid + off] : 0u;
        __syncthreads();
        part[tid] += add;
        __syncthreads();
    }
    A = (tid < 255) ? part[tid + 1] : 0u;
#pragma unroll
    for (int j = 7; j >= 0; --j) {
        uint32_t c = b8[j];
        if (A < k2 && k2 <= A + c) {
            uint32_t u = (sst.prefix << 21) | (chunk * 2048u + (uint32_t)(tid * 8 + j));
            st->u_kth = u;
            st->thr_nl = neg_loss_precise(unxform(u), -1.0f);  // t = -1 exactly
            st->done = 1u;
        }
        A += c;
    }
}

// ---------------- final: fast-math values, bit-exact mask ------------------
__device__ __forceinline__ float fin1(float xx, float tt, uint32_t ukth, float thr) {
    float lp = __logf(1.0f + __expf(-fabsf(xx)));   // HW exp/log
    float v = 0.0f;
    if (tt > 0.0f) {
        v = fmaxf(xx, 0.0f) - xx * tt + lp;
    } else if (tt < 0.0f) {
        uint32_t u = xform(__float_as_uint(xx));
        bool keep = u < ukth;
        if (keep && (ukth - u) < GUARD)             // ~0 lanes hit this
            keep = neg_loss_precise(xx, tt) < thr;
        if (keep) v = fmaxf(-xx, 0.0f) - xx * tt + lp;
    }
    return v;
}

__device__ __forceinline__ float4 fin_quad(float4 xv, float4 tv, uint32_t ukth, float thr) {
    float4 r;
    r.x = fin1(xv.x, tv.x, ukth, thr);
    r.y = fin1(xv.y, tv.y, ukth, thr);
    r.z = fin1(xv.z, tv.z, ukth, thr);
    r.w = fin1(xv.w, tv.w, ukth, thr);
    return r;
}

__global__ __launch_bounds__(256) void k_final(
        const float* __restrict__ x, const float* __restrict__ t,
        const SelState* __restrict__ st, float* __restrict__ out, int n) {
    const uint32_t ukth = st->u_kth;
    const float thr = st->thr_nl;
    const float4* x4 = (const float4*)x;
    const float4* t4 = (const float4*)t;
    float4* o4 = (float4*)out;
    const int n4 = n >> 2;
    const int S = gridDim.x * 256;
    int i = blockIdx.x * 256 + threadIdx.x;
    for (; i + 3 * S < n4; i += 4 * S) {
        float4 xa = x4[i], xb = x4[i + S], xc = x4[i + 2 * S], xd = x4[i + 3 * S];
        float4 ta = t4[i], tb = t4[i + S], tc = t4[i + 2 * S], td = t4[i + 3 * S];
        o4[i]         = fin_quad(xa, ta, ukth, thr);
        o4[i + S]     = fin_quad(xb, tb, ukth, thr);
        o4[i + 2 * S] = fin_quad(xc, tc, ukth, thr);
        o4[i + 3 * S] = fin_quad(xd, td, ukth, thr);
    }
    for (; i < n4; i += S) {
        float4 xa = x4[i], ta = t4[i];
        o4[i] = fin_quad(xa, ta, ukth, thr);
    }
    if (blockIdx.x == 0) {
        for (int j = (n4 << 2) + threadIdx.x; j < n; j += 256) {
            out[j] = fin1(x[j], t[j], ukth, thr);
        }
    }
}

extern "C" void kernel_launch(void* const* d_in, const int* in_sizes, int n_in,
                              void* d_out, int out_size, void* d_ws, size_t ws_size,
                              hipStream_t stream) {
    const float* x = (const float*)d_in[0];
    const float* t = (const float*)d_in[1];
    const int* kptr = (const int*)d_in[2];
    float* out = (float*)d_out;
    const int n = in_sizes[0];
    if (n <= 0) return;

    char* ws = (char*)d_ws;
    uint32_t* hist1 = (uint32_t*)(ws + 0);        // 2048 bins
    uint32_t* csums = (uint32_t*)(ws + 8192);     // 1024 chunk sums
    SelState* st    = (SelState*)(ws + 12288);
    uint32_t* bcnt  = (uint32_t*)(ws + 16384);    // 2048 block cursors
    uint32_t* h21   = (uint32_t*)(ws + 32768);    // 2^21 bins (8 MB)
    const size_t h21_end = 32768 + (size_t)(1u << 21) * 4u;

    const int n4 = n >> 2;
    int work = (n4 + 255) / 256;
    if (work < 1) work = 1;
    const int grid1 = work < 2048 ? work : 2048;   // compaction & consumers
    const int gridF = work < 2048 ? work : 2048;

    const int S = grid1 * 256;
    const uint32_t iters = (uint32_t)((n4 + 2 * S - 1) / (2 * S));
    uint32_t cap = iters * 8u * 256u + 8u;         // worst case: all negative
    const size_t need = h21_end + (size_t)cap * 4u * (size_t)grid1;
    uint32_t* comp = (ws_size >= need) ? (uint32_t*)(ws + h21_end) : nullptr;

    // zero meta (32 KB) + hist21 (8 MB)
    hipMemsetAsync(d_ws, 0, h21_end, stream);

    if (comp)
        k1_compact<<<grid1, 256, 0, stream>>>(x, t, comp, bcnt, cap, n);
    k1b_hist <<<grid1, 256, 0, stream>>>(comp, bcnt, cap, hist1, x, t, n);
    scan1    <<<1, 256, 0, stream>>>(hist1, st, kptr);
    k2_hist21<<<grid1, 256, 0, stream>>>(comp, bcnt, cap, h21, st, x, t, n);
    scan2a   <<<1024, 256, 0, stream>>>(h21, csums, st);
    scan2b   <<<1, 256, 0, stream>>>(h21, csums, st);
    k_final  <<<gridF, 256, 0, stream>>>(x, t, st, out, n);
}